// Round 3
// baseline (23354.108 us; speedup 1.0000x reference)
//
#include <hip/hip_runtime.h>
#include <hip/hip_bf16.h>
#include <stdint.h>

#define T_STEPS 8192
#define NX 1024
#define NU 512
#define NY 128
#define HID 4096

#define SEQ_WGS 256
#define SEQ_BLK 512

typedef __attribute__((ext_vector_type(8))) short bf16x8;
typedef __attribute__((ext_vector_type(4))) float f32x4;
typedef __attribute__((ext_vector_type(2))) short s16x2;

__device__ __forceinline__ float bf2f(ushort u) {
  union { uint32_t i; float f; } v; v.i = ((uint32_t)u) << 16; return v.f;
}
__device__ __forceinline__ ushort f2bf(float f) {
  union { float f; uint32_t i; } v; v.f = f;
  uint32_t r = v.i + 0x7fffu + ((v.i >> 16) & 1u);
  return (ushort)(r >> 16);
}
__device__ __forceinline__ float lof(uint32_t u) {
  union { uint32_t i; float f; } v; v.i = u << 16; return v.f;
}
__device__ __forceinline__ float hif(uint32_t u) {
  union { uint32_t i; float f; } v; v.i = u & 0xffff0000u; return v.f;
}

// bf16-pair dot with f32 accumulate: acc += h.lo*m.lo + h.hi*m.hi
__device__ __forceinline__ float dot2bf(uint32_t h, uint32_t m, float acc) {
#if __has_builtin(__builtin_amdgcn_fdot2_f32_bf16)
  return __builtin_amdgcn_fdot2_f32_bf16(__builtin_bit_cast(s16x2, h),
                                         __builtin_bit_cast(s16x2, m), acc, false);
#else
  acc = fmaf(lof(h), lof(m), acc);
  return fmaf(hif(h), hif(m), acc);
#endif
}

// ---------------- small utility kernels ----------------

__global__ void cvt_bf16_kernel(const float* __restrict__ in, ushort* __restrict__ out, int n) {
  int i = blockIdx.x * blockDim.x + threadIdx.x;
  int stride = gridDim.x * blockDim.x;
  for (; i < n; i += stride) out[i] = f2bf(in[i]);
}

// out[C][R] = (bf16) in[R][C]
__global__ void transpose_cvt_kernel(const float* __restrict__ in, ushort* __restrict__ out,
                                     int R, int C) {
  __shared__ float tile[32][33];
  int bx = blockIdx.x, by = blockIdx.y;
  int tx = threadIdx.x, ty = threadIdx.y;  // 32 x 8
#pragma unroll
  for (int yy = 0; yy < 4; ++yy) {
    long r = (long)by * 32 + ty + yy * 8;
    long c = (long)bx * 32 + tx;
    tile[ty + yy * 8][tx] = in[r * C + c];
  }
  __syncthreads();
#pragma unroll
  for (int yy = 0; yy < 4; ++yy) {
    long c = (long)bx * 32 + ty + yy * 8;  // out row
    long r = (long)by * 32 + tx;           // out col
    out[c * R + r] = f2bf(tile[tx][ty + yy * 8]);
  }
}

// biasDH[j] = f_b1[j] + sum_k f_b2[k] * f_w1[k][j]
__global__ void bias_dh_kernel(const float* __restrict__ fw1, const float* __restrict__ fb1,
                               const float* __restrict__ fb2, float* __restrict__ biasDH) {
  int j = blockIdx.x * blockDim.x + threadIdx.x;
  float s = fb1[j];
  for (int k = 0; k < NX; ++k) s += fb2[k] * fw1[(long)k * HID + j];
  biasDH[j] = s;
}

// z_0[j] = f_b1[j] + u0 @ W1u[:,j] + x0 @ W1x[:,j]; h_0 = tanh(z_0)
__global__ void fixup_row0_kernel(const float* __restrict__ fw1, const float* __restrict__ fb1,
                                  const float* __restrict__ u, const float* __restrict__ x0,
                                  ushort* __restrict__ DH, uint32_t* __restrict__ htag) {
  int j = blockIdx.x * blockDim.x + threadIdx.x;
  float s = fb1[j];
  for (int k = 0; k < NU; ++k) s += u[k] * fw1[(long)(NX + k) * HID + j];
  for (int k = 0; k < NX; ++k) s += x0[k] * fw1[(long)k * HID + j];
  float h = tanhf(s);
  ushort hb = f2bf(h);
  DH[j] = hb;
  htag[j] = ((uint32_t)hb << 16);  // tag = 0
}

__global__ void x0_row_kernel(const float* __restrict__ x0, ushort* __restrict__ X) {
  int j = blockIdx.x * blockDim.x + threadIdx.x;
  if (j < NX) X[j] = f2bf(x0[j]);
}

// ---------------- generic bf16 MFMA GEMM ----------------
// C[M,N] = act( A[M,K] @ B[K,N] + bias ),  B supplied transposed as BT[N,K].
// flags: 1 = tanh, 2 = fp32 output (else bf16)
#define GBM 128
#define GBN 128
#define GBK 32
#define LDT 40

__global__ __launch_bounds__(256) void gemm_kernel(
    const ushort* __restrict__ A, const ushort* __restrict__ BT,
    void* __restrict__ Cout, const float* __restrict__ bias,
    int M, int N, int K, int flags)
{
  __shared__ ushort Al[GBM * LDT];
  __shared__ ushort Bl[GBN * LDT];
  const int tid = threadIdx.x;
  const int bm = blockIdx.y, bn = blockIdx.x;
  const int wave = tid >> 6, lane = tid & 63;
  const int wr = wave >> 1, wc = wave & 1;
  const int l15 = lane & 15, l4 = lane >> 4;

  f32x4 acc[4][4];
#pragma unroll
  for (int m = 0; m < 4; ++m)
#pragma unroll
    for (int n = 0; n < 4; ++n) acc[m][n] = (f32x4){0.f, 0.f, 0.f, 0.f};

  const int r_t = tid >> 1;
  const int h_t = (tid & 1) * 16;
  const long arow = (long)bm * GBM + r_t;
  const long brow = (long)bn * GBN + r_t;

  for (int k0 = 0; k0 < K; k0 += GBK) {
    uint4 a0 = make_uint4(0,0,0,0), a1 = make_uint4(0,0,0,0);
    if (arow < M) {
      const ushort* p = A + arow * K + k0 + h_t;
      a0 = *(const uint4*)p;
      a1 = *(const uint4*)(p + 8);
    }
    const ushort* q = BT + brow * K + k0 + h_t;
    uint4 b0 = *(const uint4*)q;
    uint4 b1 = *(const uint4*)(q + 8);
    __syncthreads();
    *(uint4*)&Al[r_t * LDT + h_t]     = a0;
    *(uint4*)&Al[r_t * LDT + h_t + 8] = a1;
    *(uint4*)&Bl[r_t * LDT + h_t]     = b0;
    *(uint4*)&Bl[r_t * LDT + h_t + 8] = b1;
    __syncthreads();

    bf16x8 af[4], bfv[4];
#pragma unroll
    for (int m = 0; m < 4; ++m)
      af[m] = *(const bf16x8*)&Al[(wr * 64 + m * 16 + l15) * LDT + l4 * 8];
#pragma unroll
    for (int n = 0; n < 4; ++n)
      bfv[n] = *(const bf16x8*)&Bl[(wc * 64 + n * 16 + l15) * LDT + l4 * 8];
#pragma unroll
    for (int m = 0; m < 4; ++m)
#pragma unroll
      for (int n = 0; n < 4; ++n)
        acc[m][n] = __builtin_amdgcn_mfma_f32_16x16x32_bf16(af[m], bfv[n], acc[m][n], 0, 0, 0);
  }

  const bool f32out = (flags & 2) != 0;
  const bool dotanh = (flags & 1) != 0;
#pragma unroll
  for (int m = 0; m < 4; ++m) {
#pragma unroll
    for (int n = 0; n < 4; ++n) {
#pragma unroll
      for (int j = 0; j < 4; ++j) {
        long grow = (long)bm * GBM + wr * 64 + m * 16 + l4 * 4 + j;
        int  gcol = bn * GBN + wc * 64 + n * 16 + l15;
        if (grow < M) {
          float v = acc[m][n][j];
          if (bias) v += bias[gcol];
          if (dotanh) v = tanhf(v);
          if (f32out) ((float*)Cout)[grow * N + gcol] = v;
          else        ((ushort*)Cout)[grow * N + gcol] = f2bf(v);
        }
      }
    }
  }
}

// ---------------- persistent sequential kernel (dataflow-synced) ----------------
// h_{i+1} = tanh(h_i @ M + D[i+1]).
// Publication: tagged u32 words (bf16(h)<<16 | step), published as u64 PAIRS
// (one wave owns 2 adjacent columns -> one agent-scope relaxed u64 store).
// Consumers poll their 8 owned words as 4 u64 agent loads (tag check on low
// word only: the pair comes from a single atomic store).
// Ping-pong depth 2 over htag[2][HID] is overwrite-safe (see round-1 argument).
// M is register-resident PACKED bf16: wave w holds cols {2w,2w+1}; lane l holds
// k in {8l+512j | j=0..7} as uint4s; dot via v_dot2_f32_bf16 (f32 accumulate).
__global__ __launch_bounds__(SEQ_BLK, 1) void seq_kernel(
    const ushort* __restrict__ MT, ushort* __restrict__ DH,
    uint32_t* __restrict__ htag, int nsteps)
{
  __shared__ ushort hl[HID];          // 8 KB staging for h_i
  const int tid = threadIdx.x;
  const int w = threadIdx.x >> 6;     // wave 0..7
  const int lane = tid & 63;
  const int c0 = (blockIdx.x << 4) + (w << 1);   // this wave's first column

  // M fragments: packed bf16 pairs, 2 columns x 8 uint4 = 64 VGPRs
  uint4 mA[8], mB[8];
  {
    const uint4* rA = (const uint4*)(MT + (size_t)c0 * HID);
    const uint4* rB = (const uint4*)(MT + (size_t)(c0 + 1) * HID);
#pragma unroll
    for (int j = 0; j < 8; ++j) {
      mA[j] = rA[lane + 64 * j];
      mB[j] = rB[lane + 64 * j];
    }
  }

  const bool prod = (lane == 0);
  unsigned long long* tagbase = (unsigned long long*)htag;

  for (int i = 0; i < nsteps; ++i) {
    // Prefetch D_{i+1} for both columns (one dword: cols 2w,2w+1 adjacent).
    float dA = 0.f, dB = 0.f;
    if (prod) {
      uint32_t dw = *(const uint32_t*)(DH + (size_t)(i + 1) * HID + c0);
      dA = lof(dw); dB = hif(dw);
    }

    // ---- poll own 8 words (4 u64) of slot i&1 ----
    unsigned long long x0, x1, x2, x3;
    {
      unsigned long long* slot = tagbase + (size_t)(i & 1) * (HID / 2) + (tid << 2);
      const uint32_t tg = (uint32_t)i & 0xffffu;
      for (;;) {
        x0 = __hip_atomic_load(slot + 0, __ATOMIC_RELAXED, __HIP_MEMORY_SCOPE_AGENT);
        x1 = __hip_atomic_load(slot + 1, __ATOMIC_RELAXED, __HIP_MEMORY_SCOPE_AGENT);
        x2 = __hip_atomic_load(slot + 2, __ATOMIC_RELAXED, __HIP_MEMORY_SCOPE_AGENT);
        x3 = __hip_atomic_load(slot + 3, __ATOMIC_RELAXED, __HIP_MEMORY_SCOPE_AGENT);
        uint32_t bad = (((uint32_t)x0 ^ tg) | ((uint32_t)x1 ^ tg) |
                        ((uint32_t)x2 ^ tg) | ((uint32_t)x3 ^ tg)) & 0xffffu;
        if (bad == 0) break;
        __builtin_amdgcn_s_sleep(1);
      }
    }
    __syncthreads();   // everyone done READING hl from previous iteration
    // stage: extract 8 bf16, pack to 4 dwords, one ds_write_b128
    {
      uint4 p;
      p.x = ((uint32_t)(x0 >> 16) & 0xffffu) | ((uint32_t)(x0 >> 32) & 0xffff0000u);
      p.y = ((uint32_t)(x1 >> 16) & 0xffffu) | ((uint32_t)(x1 >> 32) & 0xffff0000u);
      p.z = ((uint32_t)(x2 >> 16) & 0xffffu) | ((uint32_t)(x2 >> 32) & 0xffff0000u);
      p.w = ((uint32_t)(x3 >> 16) & 0xffffu) | ((uint32_t)(x3 >> 32) & 0xffff0000u);
      ((uint4*)hl)[tid] = p;
    }
    __syncthreads();

    // ---- dot over this lane's k-slice for both columns ----
    float accA = 0.f, accB = 0.f;
    const uint4* h4 = (const uint4*)hl;
#pragma unroll
    for (int j = 0; j < 8; ++j) {
      uint4 hv = h4[lane + 64 * j];
      accA = dot2bf(hv.x, mA[j].x, accA);
      accB = dot2bf(hv.x, mB[j].x, accB);
      accA = dot2bf(hv.y, mA[j].y, accA);
      accB = dot2bf(hv.y, mB[j].y, accB);
      accA = dot2bf(hv.z, mA[j].z, accA);
      accB = dot2bf(hv.z, mB[j].z, accB);
      accA = dot2bf(hv.w, mA[j].w, accA);
      accB = dot2bf(hv.w, mB[j].w, accB);
    }
#pragma unroll
    for (int off = 32; off >= 1; off >>= 1) {
      accA += __shfl_xor(accA, off, 64);
      accB += __shfl_xor(accB, off, 64);
    }

    if (prod) {
      ushort ha = f2bf(tanhf(accA + dA));
      ushort hb = f2bf(tanhf(accB + dB));
      uint32_t tg1 = (uint32_t)(i + 1) & 0xffffu;
      unsigned long long word =
          ((unsigned long long)(((uint32_t)hb << 16) | tg1) << 32) |
          (unsigned long long)(((uint32_t)ha << 16) | tg1);
      __hip_atomic_store(tagbase + (size_t)((i + 1) & 1) * (HID / 2) + (c0 >> 1), word,
                         __ATOMIC_RELAXED, __HIP_MEMORY_SCOPE_AGENT);
      *(uint32_t*)(DH + (size_t)(i + 1) * HID + c0) = (uint32_t)ha | ((uint32_t)hb << 16);
    }
  }
}

// ---------------- launch ----------------

extern "C" void kernel_launch(void* const* d_in, const int* in_sizes, int n_in,
                              void* d_out, int out_size, void* d_ws, size_t ws_size,
                              hipStream_t stream) {
  const float* x0  = (const float*)d_in[0];
  const float* u   = (const float*)d_in[1];
  const float* fw1 = (const float*)d_in[2];
  const float* fb1 = (const float*)d_in[3];
  const float* fw2 = (const float*)d_in[4];
  const float* fb2 = (const float*)d_in[5];
  const float* gw1 = (const float*)d_in[6];
  const float* gb1 = (const float*)d_in[7];
  const float* gw2 = (const float*)d_in[8];
  const float* gb2 = (const float*)d_in[9];
  float* out = (float*)d_out;

  char* ws = (char*)d_ws;
  size_t off = 0;
  auto alloc = [&](size_t bytes) -> char* {
    char* p = ws + off; off += (bytes + 255) & ~(size_t)255; return p;
  };
  ushort* MT     = (ushort*)alloc((size_t)HID * HID * 2);
  ushort* DH     = (ushort*)alloc((size_t)T_STEPS * HID * 2);
  ushort* X      = (ushort*)alloc((size_t)T_STEPS * NX * 2);
  ushort* W1xT   = (ushort*)alloc((size_t)HID * NX * 2);
  ushort* W1uT   = (ushort*)alloc((size_t)HID * NU * 2);
  ushort* W2bf   = (ushort*)alloc((size_t)HID * NX * 2);
  ushort* W2T    = (ushort*)alloc((size_t)NX * HID * 2);
  ushort* Gw1T   = (ushort*)alloc((size_t)HID * NX * 2);
  ushort* Gw2T   = (ushort*)alloc((size_t)NY * HID * 2);
  ushort* Ubf    = (ushort*)alloc((size_t)T_STEPS * NU * 2);
  float*  biasDH = (float*)alloc((size_t)HID * 4);
  uint32_t* htag = (uint32_t*)alloc((size_t)2 * HID * 4);
  if (off > ws_size) return;  // workspace too small; bail

  cvt_bf16_kernel<<<2048, 256, 0, stream>>>(u, Ubf, T_STEPS * NU);
  cvt_bf16_kernel<<<2048, 256, 0, stream>>>(fw2, W2bf, HID * NX);
  transpose_cvt_kernel<<<dim3(HID/32, NX/32), dim3(32, 8), 0, stream>>>(fw1, W1xT, NX, HID);
  transpose_cvt_kernel<<<dim3(HID/32, NU/32), dim3(32, 8), 0, stream>>>(fw1 + (size_t)NX * HID, W1uT, NU, HID);
  transpose_cvt_kernel<<<dim3(NX/32, HID/32), dim3(32, 8), 0, stream>>>(fw2, W2T, HID, NX);
  transpose_cvt_kernel<<<dim3(HID/32, NX/32), dim3(32, 8), 0, stream>>>(gw1, Gw1T, NX, HID);
  transpose_cvt_kernel<<<dim3(NY/32, HID/32), dim3(32, 8), 0, stream>>>(gw2, Gw2T, HID, NY);
  bias_dh_kernel<<<HID/256, 256, 0, stream>>>(fw1, fb1, fb2, biasDH);

  // MT[j][k] = M[k][j] = sum_p W2[k][p] * W1x[p][j]
  gemm_kernel<<<dim3(HID/128, HID/128), 256, 0, stream>>>(W1xT, W2bf, MT, nullptr, HID, HID, NX, 0);
  // DH = Ubf @ W1u + (b1 + b2@W1x)
  gemm_kernel<<<dim3(HID/128, T_STEPS/128), 256, 0, stream>>>(Ubf, W1uT, DH, biasDH, T_STEPS, HID, NU, 0);
  // h_0 into DH row 0 + tagged slot 0
  fixup_row0_kernel<<<HID/256, 256, 0, stream>>>(fw1, fb1, u, x0, DH, htag);

  // sequential recurrence: h_{i+1} = tanh(h_i @ M + D[i+1]), i = 0..8189
  {
    int nsteps = T_STEPS - 2;  // produce h_1 .. h_8190
    void* MT_p = (void*)MT; void* DH_p = (void*)DH; void* ht_p = (void*)htag;
    void* args[] = { &MT_p, &DH_p, &ht_p, &nsteps };
    hipError_t e = hipLaunchCooperativeKernel((const void*)seq_kernel, dim3(SEQ_WGS),
                                              dim3(SEQ_BLK), args, 0, stream);
    if (e != hipSuccess) {
      (void)hipGetLastError();
      seq_kernel<<<SEQ_WGS, SEQ_BLK, 0, stream>>>(MT, DH, htag, nsteps);
    }
  }

  x0_row_kernel<<<NX/256, 256, 0, stream>>>(x0, X);
  // X[1..8191] = H[0..8190] @ W2 + b2
  gemm_kernel<<<dim3(NX/128, T_STEPS/128), 256, 0, stream>>>(DH, W2T, X + NX, fb2, T_STEPS - 1, NX, HID, 0);
  // G = tanh(X @ g_w1 + g_b1) -> reuse DH buffer
  gemm_kernel<<<dim3(HID/128, T_STEPS/128), 256, 0, stream>>>(X, Gw1T, DH, gb1, T_STEPS, HID, NX, 1);
  // Y = G @ g_w2 + g_b2 -> fp32 out
  gemm_kernel<<<dim3(NY/128, T_STEPS/128), 256, 0, stream>>>(DH, Gw2T, out, gb2, T_STEPS, NY, HID, 2);
}

// Round 4
// 18933.418 us; speedup vs baseline: 1.2335x; 1.2335x over previous
//
#include <hip/hip_runtime.h>
#include <hip/hip_bf16.h>
#include <stdint.h>

#define T_STEPS 8192
#define NX 1024
#define NU 512
#define NY 128
#define HID 4096

#define SEQ_WGS 256
#define SEQ_BLK 512
#define RING 128          // tagged-row ring depth (128 x 16 KB = 2 MB)

typedef __attribute__((ext_vector_type(8))) short bf16x8;
typedef __attribute__((ext_vector_type(4))) float f32x4;
typedef __attribute__((ext_vector_type(2))) short s16x2;

__device__ __forceinline__ float bf2f(ushort u) {
  union { uint32_t i; float f; } v; v.i = ((uint32_t)u) << 16; return v.f;
}
__device__ __forceinline__ ushort f2bf(float f) {
  union { float f; uint32_t i; } v; v.f = f;
  uint32_t r = v.i + 0x7fffu + ((v.i >> 16) & 1u);
  return (ushort)(r >> 16);
}
__device__ __forceinline__ float lof(uint32_t u) {
  union { uint32_t i; float f; } v; v.i = u << 16; return v.f;
}
__device__ __forceinline__ float hif(uint32_t u) {
  union { uint32_t i; float f; } v; v.i = u & 0xffff0000u; return v.f;
}

// bf16-pair dot with f32 accumulate: acc += h.lo*m.lo + h.hi*m.hi
__device__ __forceinline__ float dot2bf(uint32_t h, uint32_t m, float acc) {
#if __has_builtin(__builtin_amdgcn_fdot2_f32_bf16)
  return __builtin_amdgcn_fdot2_f32_bf16(__builtin_bit_cast(s16x2, h),
                                         __builtin_bit_cast(s16x2, m), acc, false);
#else
  acc = fmaf(lof(h), lof(m), acc);
  return fmaf(hif(h), hif(m), acc);
#endif
}

// spin-fix a stale tagged word via cache-bypassing atomic loads
__device__ __forceinline__ void fixw(uint32_t& x, uint32_t* wp, uint32_t tg) {
  while ((x & 0xffffu) != tg)
    x = __hip_atomic_load(wp, __ATOMIC_RELAXED, __HIP_MEMORY_SCOPE_AGENT);
}

// ---------------- small utility kernels ----------------

__global__ void cvt_bf16_kernel(const float* __restrict__ in, ushort* __restrict__ out, int n) {
  int i = blockIdx.x * blockDim.x + threadIdx.x;
  int stride = gridDim.x * blockDim.x;
  for (; i < n; i += stride) out[i] = f2bf(in[i]);
}

// out[C][R] = (bf16) in[R][C]
__global__ void transpose_cvt_kernel(const float* __restrict__ in, ushort* __restrict__ out,
                                     int R, int C) {
  __shared__ float tile[32][33];
  int bx = blockIdx.x, by = blockIdx.y;
  int tx = threadIdx.x, ty = threadIdx.y;  // 32 x 8
#pragma unroll
  for (int yy = 0; yy < 4; ++yy) {
    long r = (long)by * 32 + ty + yy * 8;
    long c = (long)bx * 32 + tx;
    tile[ty + yy * 8][tx] = in[r * C + c];
  }
  __syncthreads();
#pragma unroll
  for (int yy = 0; yy < 4; ++yy) {
    long c = (long)bx * 32 + ty + yy * 8;  // out row
    long r = (long)by * 32 + tx;           // out col
    out[c * R + r] = f2bf(tile[tx][ty + yy * 8]);
  }
}

// biasDH[j] = f_b1[j] + sum_k f_b2[k] * f_w1[k][j]
__global__ void bias_dh_kernel(const float* __restrict__ fw1, const float* __restrict__ fb1,
                               const float* __restrict__ fb2, float* __restrict__ biasDH) {
  int j = blockIdx.x * blockDim.x + threadIdx.x;
  float s = fb1[j];
  for (int k = 0; k < NX; ++k) s += fb2[k] * fw1[(long)k * HID + j];
  biasDH[j] = s;
}

// z_0[j] = f_b1[j] + u0 @ W1u[:,j] + x0 @ W1x[:,j]; h_0 = tanh(z_0)
// Publish h_0 into DH row 0 and tagged ring slot 0 (tag = 0).
__global__ void fixup_row0_kernel(const float* __restrict__ fw1, const float* __restrict__ fb1,
                                  const float* __restrict__ u, const float* __restrict__ x0,
                                  ushort* __restrict__ DH, uint32_t* __restrict__ HTAG) {
  int j = blockIdx.x * blockDim.x + threadIdx.x;
  float s = fb1[j];
  for (int k = 0; k < NU; ++k) s += u[k] * fw1[(long)(NX + k) * HID + j];
  for (int k = 0; k < NX; ++k) s += x0[k] * fw1[(long)k * HID + j];
  float h = tanhf(s);
  ushort hb = f2bf(h);
  DH[j] = hb;
  HTAG[j] = ((uint32_t)hb << 16);  // tag = 0
}

__global__ void x0_row_kernel(const float* __restrict__ x0, ushort* __restrict__ X) {
  int j = blockIdx.x * blockDim.x + threadIdx.x;
  if (j < NX) X[j] = f2bf(x0[j]);
}

// ---------------- generic bf16 MFMA GEMM ----------------
// C[M,N] = act( A[M,K] @ B[K,N] + bias ),  B supplied transposed as BT[N,K].
// flags: 1 = tanh, 2 = fp32 output (else bf16)
#define GBM 128
#define GBN 128
#define GBK 32
#define LDT 40

__global__ __launch_bounds__(256) void gemm_kernel(
    const ushort* __restrict__ A, const ushort* __restrict__ BT,
    void* __restrict__ Cout, const float* __restrict__ bias,
    int M, int N, int K, int flags)
{
  __shared__ ushort Al[GBM * LDT];
  __shared__ ushort Bl[GBN * LDT];
  const int tid = threadIdx.x;
  const int bm = blockIdx.y, bn = blockIdx.x;
  const int wave = tid >> 6, lane = tid & 63;
  const int wr = wave >> 1, wc = wave & 1;
  const int l15 = lane & 15, l4 = lane >> 4;

  f32x4 acc[4][4];
#pragma unroll
  for (int m = 0; m < 4; ++m)
#pragma unroll
    for (int n = 0; n < 4; ++n) acc[m][n] = (f32x4){0.f, 0.f, 0.f, 0.f};

  const int r_t = tid >> 1;
  const int h_t = (tid & 1) * 16;
  const long arow = (long)bm * GBM + r_t;
  const long brow = (long)bn * GBN + r_t;

  for (int k0 = 0; k0 < K; k0 += GBK) {
    uint4 a0 = make_uint4(0,0,0,0), a1 = make_uint4(0,0,0,0);
    if (arow < M) {
      const ushort* p = A + arow * K + k0 + h_t;
      a0 = *(const uint4*)p;
      a1 = *(const uint4*)(p + 8);
    }
    const ushort* q = BT + brow * K + k0 + h_t;
    uint4 b0 = *(const uint4*)q;
    uint4 b1 = *(const uint4*)(q + 8);
    __syncthreads();
    *(uint4*)&Al[r_t * LDT + h_t]     = a0;
    *(uint4*)&Al[r_t * LDT + h_t + 8] = a1;
    *(uint4*)&Bl[r_t * LDT + h_t]     = b0;
    *(uint4*)&Bl[r_t * LDT + h_t + 8] = b1;
    __syncthreads();

    bf16x8 af[4], bfv[4];
#pragma unroll
    for (int m = 0; m < 4; ++m)
      af[m] = *(const bf16x8*)&Al[(wr * 64 + m * 16 + l15) * LDT + l4 * 8];
#pragma unroll
    for (int n = 0; n < 4; ++n)
      bfv[n] = *(const bf16x8*)&Bl[(wc * 64 + n * 16 + l15) * LDT + l4 * 8];
#pragma unroll
    for (int m = 0; m < 4; ++m)
#pragma unroll
      for (int n = 0; n < 4; ++n)
        acc[m][n] = __builtin_amdgcn_mfma_f32_16x16x32_bf16(af[m], bfv[n], acc[m][n], 0, 0, 0);
  }

  const bool f32out = (flags & 2) != 0;
  const bool dotanh = (flags & 1) != 0;
#pragma unroll
  for (int m = 0; m < 4; ++m) {
#pragma unroll
    for (int n = 0; n < 4; ++n) {
#pragma unroll
      for (int j = 0; j < 4; ++j) {
        long grow = (long)bm * GBM + wr * 64 + m * 16 + l4 * 4 + j;
        int  gcol = bn * GBN + wc * 64 + n * 16 + l15;
        if (grow < M) {
          float v = acc[m][n][j];
          if (bias) v += bias[gcol];
          if (dotanh) v = tanhf(v);
          if (f32out) ((float*)Cout)[grow * N + gcol] = v;
          else        ((ushort*)Cout)[grow * N + gcol] = f2bf(v);
        }
      }
    }
  }
}

// ---------------- persistent sequential kernel (sentinel + bulk ring) ----------------
// h_{i+1} = tanh(h_i @ M + D[i+1]).
// Ring of RING tagged rows, one per step: word = (bf16(h)<<16) | (step & 0xffff).
// Producers: one u64 agent-scope store per wave (2 adjacent columns).
// Consumers: (1) 256 threads poll ONE sentinel word per producer-WG via agent
// atomics (tiny traffic); (2) bulk-read the whole 16 KB row with coalesced
// NORMAL dwordx4 loads — each ring address is read once per 128 steps, so own-L2
// copies are long-evicted; any stale word is detected by its tag and re-fetched
// with a cache-bypassing atomic (correctness never depends on cache behavior;
// 0xAA-poison tag = 0xAAAA is outside the 0..8190 step range).
// WG skew is <=1 step (producing h_{i+1} needs all of h_i), so ring reuse after
// 128 steps can never overwrite live data.
__global__ __launch_bounds__(SEQ_BLK, 1) void seq_kernel(
    const ushort* __restrict__ MT, ushort* __restrict__ DH,
    uint32_t* __restrict__ HTAG, int nsteps)
{
  __shared__ ushort hl[HID];          // 8 KB staging for h_i (packed bf16)
  const int tid = threadIdx.x;
  const int w = tid >> 6;             // wave 0..7
  const int lane = tid & 63;
  const int c0 = (blockIdx.x << 4) + (w << 1);   // this wave's first column

  // M fragments: packed bf16, 2 columns x 8 uint4 = 64 VGPRs
  uint4 mA[8], mB[8];
  {
    const uint4* rA = (const uint4*)(MT + (size_t)c0 * HID);
    const uint4* rB = (const uint4*)(MT + (size_t)(c0 + 1) * HID);
#pragma unroll
    for (int j = 0; j < 8; ++j) {
      mA[j] = rA[lane + 64 * j];
      mB[j] = rB[lane + 64 * j];
    }
  }

  const bool prod = (lane == 0);

  for (int i = 0; i < nsteps; ++i) {
    const uint32_t tg = (uint32_t)i & 0xffffu;
    uint32_t* rowp = HTAG + (size_t)(i & (RING - 1)) * HID;

    // Prefetch D_{i+1} for both columns (own dword; only this wave touches it).
    float dA = 0.f, dB = 0.f;
    if (prod) {
      uint32_t dw = *(const uint32_t*)(DH + (size_t)(i + 1) * HID + c0);
      dA = lof(dw); dB = hif(dw);
    }

    // ---- sentinel poll: one word per producer WG (word 16p+15) ----
    if (tid < SEQ_WGS) {
      uint32_t* sp = rowp + tid * 16 + 15;
      while ((__hip_atomic_load(sp, __ATOMIC_RELAXED, __HIP_MEMORY_SCOPE_AGENT)
              & 0xffffu) != tg)
        __builtin_amdgcn_s_sleep(1);
    }
    __syncthreads();   // sentinels seen; also: prev iter's hl reads complete

    // ---- bulk load (coalesced, cached) + tag verify + stage to LDS ----
    {
      const uint4* rv = (const uint4*)rowp;
      uint4 v0 = rv[tid];
      uint4 v1 = rv[tid + 512];
      uint32_t bad0 = ((v0.x ^ tg) | (v0.y ^ tg) | (v0.z ^ tg) | (v0.w ^ tg)) & 0xffffu;
      if (__builtin_expect(bad0 != 0, 0)) {
        uint32_t* wp = rowp + tid * 4;
        fixw(v0.x, wp + 0, tg); fixw(v0.y, wp + 1, tg);
        fixw(v0.z, wp + 2, tg); fixw(v0.w, wp + 3, tg);
      }
      uint32_t bad1 = ((v1.x ^ tg) | (v1.y ^ tg) | (v1.z ^ tg) | (v1.w ^ tg)) & 0xffffu;
      if (__builtin_expect(bad1 != 0, 0)) {
        uint32_t* wp = rowp + tid * 4 + 2048;
        fixw(v1.x, wp + 0, tg); fixw(v1.y, wp + 1, tg);
        fixw(v1.z, wp + 2, tg); fixw(v1.w, wp + 3, tg);
      }
      unsigned long long* hl64 = (unsigned long long*)hl;
      uint32_t p0 = (v0.x >> 16) | (v0.y & 0xffff0000u);
      uint32_t p1 = (v0.z >> 16) | (v0.w & 0xffff0000u);
      hl64[tid] = ((unsigned long long)p1 << 32) | p0;
      p0 = (v1.x >> 16) | (v1.y & 0xffff0000u);
      p1 = (v1.z >> 16) | (v1.w & 0xffff0000u);
      hl64[tid + 512] = ((unsigned long long)p1 << 32) | p0;
    }
    __syncthreads();

    // ---- dot over this lane's k-slice for both columns ----
    float accA = 0.f, accB = 0.f;
    const uint4* h4 = (const uint4*)hl;
#pragma unroll
    for (int j = 0; j < 8; ++j) {
      uint4 hv = h4[lane + 64 * j];
      accA = dot2bf(hv.x, mA[j].x, accA);
      accB = dot2bf(hv.x, mB[j].x, accB);
      accA = dot2bf(hv.y, mA[j].y, accA);
      accB = dot2bf(hv.y, mB[j].y, accB);
      accA = dot2bf(hv.z, mA[j].z, accA);
      accB = dot2bf(hv.z, mB[j].z, accB);
      accA = dot2bf(hv.w, mA[j].w, accA);
      accB = dot2bf(hv.w, mB[j].w, accB);
    }
    // dual reduce: fold halves, then butterfly within each half (7 shuffle-adds)
    accA += __shfl_xor(accA, 32, 64);
    accB += __shfl_xor(accB, 32, 64);
    float y = (lane < 32) ? accA : accB;
#pragma unroll
    for (int off = 16; off >= 1; off >>= 1)
      y += __shfl_xor(y, off, 64);
    float totB = __shfl(y, 32, 64);   // lane0 receives B total

    if (prod) {
      ushort ha = f2bf(tanhf(y + dA));
      ushort hb = f2bf(tanhf(totB + dB));
      uint32_t tg1 = (uint32_t)(i + 1) & 0xffffu;
      unsigned long long word =
          ((unsigned long long)(((uint32_t)hb << 16) | tg1) << 32) |
          (unsigned long long)(((uint32_t)ha << 16) | tg1);
      unsigned long long* dst =
          (unsigned long long*)(HTAG + (size_t)((i + 1) & (RING - 1)) * HID) + (c0 >> 1);
      __hip_atomic_store(dst, word, __ATOMIC_RELAXED, __HIP_MEMORY_SCOPE_AGENT);
      *(uint32_t*)(DH + (size_t)(i + 1) * HID + c0) = (uint32_t)ha | ((uint32_t)hb << 16);
    }
  }
}

// ---------------- launch ----------------

extern "C" void kernel_launch(void* const* d_in, const int* in_sizes, int n_in,
                              void* d_out, int out_size, void* d_ws, size_t ws_size,
                              hipStream_t stream) {
  const float* x0  = (const float*)d_in[0];
  const float* u   = (const float*)d_in[1];
  const float* fw1 = (const float*)d_in[2];
  const float* fb1 = (const float*)d_in[3];
  const float* fw2 = (const float*)d_in[4];
  const float* fb2 = (const float*)d_in[5];
  const float* gw1 = (const float*)d_in[6];
  const float* gb1 = (const float*)d_in[7];
  const float* gw2 = (const float*)d_in[8];
  const float* gb2 = (const float*)d_in[9];
  float* out = (float*)d_out;

  char* ws = (char*)d_ws;
  size_t off = 0;
  auto alloc = [&](size_t bytes) -> char* {
    char* p = ws + off; off += (bytes + 255) & ~(size_t)255; return p;
  };
  ushort* MT     = (ushort*)alloc((size_t)HID * HID * 2);
  ushort* DH     = (ushort*)alloc((size_t)T_STEPS * HID * 2);
  ushort* X      = (ushort*)alloc((size_t)T_STEPS * NX * 2);
  ushort* W1xT   = (ushort*)alloc((size_t)HID * NX * 2);
  ushort* W1uT   = (ushort*)alloc((size_t)HID * NU * 2);
  ushort* W2bf   = (ushort*)alloc((size_t)HID * NX * 2);
  ushort* W2T    = (ushort*)alloc((size_t)NX * HID * 2);
  ushort* Gw1T   = (ushort*)alloc((size_t)HID * NX * 2);
  ushort* Gw2T   = (ushort*)alloc((size_t)NY * HID * 2);
  ushort* Ubf    = (ushort*)alloc((size_t)T_STEPS * NU * 2);
  float*  biasDH = (float*)alloc((size_t)HID * 4);
  uint32_t* HTAG = (uint32_t*)alloc((size_t)RING * HID * 4);
  if (off > ws_size) return;  // workspace too small; bail

  cvt_bf16_kernel<<<2048, 256, 0, stream>>>(u, Ubf, T_STEPS * NU);
  cvt_bf16_kernel<<<2048, 256, 0, stream>>>(fw2, W2bf, HID * NX);
  transpose_cvt_kernel<<<dim3(HID/32, NX/32), dim3(32, 8), 0, stream>>>(fw1, W1xT, NX, HID);
  transpose_cvt_kernel<<<dim3(HID/32, NU/32), dim3(32, 8), 0, stream>>>(fw1 + (size_t)NX * HID, W1uT, NU, HID);
  transpose_cvt_kernel<<<dim3(NX/32, HID/32), dim3(32, 8), 0, stream>>>(fw2, W2T, HID, NX);
  transpose_cvt_kernel<<<dim3(HID/32, NX/32), dim3(32, 8), 0, stream>>>(gw1, Gw1T, NX, HID);
  transpose_cvt_kernel<<<dim3(NY/32, HID/32), dim3(32, 8), 0, stream>>>(gw2, Gw2T, HID, NY);
  bias_dh_kernel<<<HID/256, 256, 0, stream>>>(fw1, fb1, fb2, biasDH);

  // MT[j][k] = M[k][j] = sum_p W2[k][p] * W1x[p][j]
  gemm_kernel<<<dim3(HID/128, HID/128), 256, 0, stream>>>(W1xT, W2bf, MT, nullptr, HID, HID, NX, 0);
  // DH = Ubf @ W1u + (b1 + b2@W1x)
  gemm_kernel<<<dim3(HID/128, T_STEPS/128), 256, 0, stream>>>(Ubf, W1uT, DH, biasDH, T_STEPS, HID, NU, 0);
  // h_0 into DH row 0 + tagged ring slot 0
  fixup_row0_kernel<<<HID/256, 256, 0, stream>>>(fw1, fb1, u, x0, DH, HTAG);

  // sequential recurrence: h_{i+1} = tanh(h_i @ M + D[i+1]), i = 0..8189
  {
    int nsteps = T_STEPS - 2;  // produce h_1 .. h_8190
    void* MT_p = (void*)MT; void* DH_p = (void*)DH; void* ht_p = (void*)HTAG;
    void* args[] = { &MT_p, &DH_p, &ht_p, &nsteps };
    hipError_t e = hipLaunchCooperativeKernel((const void*)seq_kernel, dim3(SEQ_WGS),
                                              dim3(SEQ_BLK), args, 0, stream);
    if (e != hipSuccess) {
      (void)hipGetLastError();
      seq_kernel<<<SEQ_WGS, SEQ_BLK, 0, stream>>>(MT, DH, HTAG, nsteps);
    }
  }

  x0_row_kernel<<<NX/256, 256, 0, stream>>>(x0, X);
  // X[1..8191] = H[0..8190] @ W2 + b2
  gemm_kernel<<<dim3(NX/128, T_STEPS/128), 256, 0, stream>>>(DH, W2T, X + NX, fb2, T_STEPS - 1, NX, HID, 0);
  // G = tanh(X @ g_w1 + g_b1) -> reuse DH buffer
  gemm_kernel<<<dim3(HID/128, T_STEPS/128), 256, 0, stream>>>(X, Gw1T, DH, gb1, T_STEPS, HID, NX, 1);
  // Y = G @ g_w2 + g_b2 -> fp32 out
  gemm_kernel<<<dim3(NY/128, T_STEPS/128), 256, 0, stream>>>(DH, Gw2T, out, gb2, T_STEPS, NY, HID, 2);
}